// Round 8
// baseline (286.654 us; speedup 1.0000x reference)
//
#include <hip/hip_runtime.h>
#include <cstdint>
#include <cstddef>

// COINBlock (RetNet-style retention, parallel form) on MI355X.
// Shapes: B=2, T=4096, I=C=1024.
//   Q = X@Wq, K = X@Wk, V = X@Wv            (bf16 MFMA, fp32 accum)
//   P = (Q K^T) * D,  D[n,m] = g^(n-m)*[n>=m]   (lower-tri tiles only)
//   out^T[i][t] = sum_m V^T[i][m] * P[t][m]     (output IS the transposed layout)
// All GEMMs are gemm_bt form: C[m][n] = sum_k A[m][k]*B[n][k], k-contiguous.
//
// R14 post-mortem (FAILED absmax 0.094): two races.
//   (1) prologue read-before-barrier: vmcnt is PER-WAVE; reading LDS rows
//       staged by other waves before the barrier = garbage. Fix: VMC->BAR->read.
//   (2) gemm4p4 staged into a slot whose ds_reads (issued one body earlier)
//       were consumed by MFMA only AFTER the stage issued -> queued-read vs
//       DMA-write order undefined. Fix: every stage targets a slot whose last
//       read was MFMA-consumed >=1 body before the stage issues.
// R15: gemm8p (proj+scores, 256x256, hazard-clean by audit) prologue fixed;
//   gemm4p3 (pv, 128x128) rebuilt with A,B BOTH 3-slot (96 KB, 1 block/CU):
//   stage A(t+2)@P_A(t), B(t+2)@P_B(t) into slot (t+2)%3 (last consumed
//   P_B(t-1), previous body); reads covered 2-3 bodies; vmcnt(4) per body.
//   scores moved to gemm8p at 256^2: 136/batch -> 272 blocks (~1.06 rounds).
// R16: identical resubmit of R15 (bench infra failed; no data to act on).

using bf16x8 = __attribute__((ext_vector_type(8))) short;
using s16x4  = __attribute__((ext_vector_type(4))) short;
using f32x4  = __attribute__((ext_vector_type(4))) float;

#define T_SEQ 4096
#define C_DIM 1024

static constexpr float L2G = -0.0144995697f; // log2(0.99)

__device__ __forceinline__ short f2bf(float f) {
  unsigned u = __builtin_bit_cast(unsigned, f);
  u += 0x7FFFu + ((u >> 16) & 1u);   // round-to-nearest-even
  return (short)(u >> 16);
}

// async 16B/lane global->LDS (dest = wave-uniform base + lane*16).
__device__ __forceinline__ void async_ld16(const short* g, const short* l) {
  __builtin_amdgcn_global_load_lds(
      (const __attribute__((address_space(1))) unsigned int*)(uintptr_t)g,
      (__attribute__((address_space(3))) unsigned int*)(unsigned)(uintptr_t)l,
      16, 0, 0);
}

#define FENCE asm volatile("" ::: "memory")
#define BAR   do { FENCE; __builtin_amdgcn_s_barrier(); FENCE; } while (0)
#define VMC(N) asm volatile("s_waitcnt vmcnt(" #N ")" ::: "memory")

// ==================== 8-wave 256x256 pipelined core (proj/scores) ====================
// 8 waves (wM=wave>>2, wN=wave&3), per-wave 128x64, BK=64, NT>=2 K-tiles.
// LDS: lsA/lsB 2 slots x 16384 shorts (128 KB total). Swizzle: LDS[R][u8] =
// G[R][u8 ^ (R&7)] (8-short units); readers XOR with row key.
// Bodies (1 barrier each; every MFMA's operands read one body earlier):
//  P1(t): rd af03k1(t)+bfk1(t) [8]; stage A(t+1); MFMA mi0-3 kk0 (af03k0,bfk0)
//  P2(t): rd af47k0(t) [4];                       MFMA mi0-3 kk1 (af03k1,bfk1)
//  P3(t): rd af47k1(t) [4]; stage B(t+2);         MFMA mi4-7 kk0; vmcnt(4|0)
//  P4(t): rd af03k0(t+1)+bfk0(t+1) [8, guarded];  MFMA mi4-7 kk1
// Hazard audit: stage A(t+1)@P1(t): slot's last reads (af of t-1) consumed by
// P4(t-1) MFMA = previous body. Stage B(t+2)@P3(t): bfk1(t) reads consumed at
// P2(t). P4 reads need A(t+1) [P1(t)] + B(t+1) [P3(t-1)]: vmcnt(4)@P3-end
// allows only B(t+2) in flight; BAR makes it chip-wide. Register names all
// use-before-rewrite. Prologue: VMC(4) -> BAR -> read (chip-wide, R14 fix).
__device__ __forceinline__ void gemm8p(
    const short* __restrict__ A, const short* __restrict__ B,
    int lda, int ldb, int NT,
    short* __restrict__ lsA, short* __restrict__ lsB,
    f32x4 (&acc)[8][4])
{
  const int tid  = threadIdx.x;
  const int lane = tid & 63;
  const int wave = tid >> 6;               // 0..7
  const int wM   = wave >> 2;
  const int wN   = wave & 3;
  const int quad = lane >> 4;
  const int l15  = lane & 15;
  const int key  = l15 & 7;
  const int uk0  = (quad ^ key) * 8;
  const int uk1  = ((4 ^ quad) ^ key) * 8;
  const short* aB0 = lsA + wM * 8192 + l15 * 64 + uk0;
  const short* aB1 = lsA + wM * 8192 + l15 * 64 + uk1;
  const short* bB0 = lsB + wN * 4096 + l15 * 64 + uk0;
  const short* bB1 = lsB + wN * 4096 + l15 * 64 + uk1;
  const int rl0 = lane >> 3;
  const int cu  = ((lane & 7) ^ rl0) * 8;
  const short* pa[4];
  const short* pb[4];
#pragma unroll
  for (int j = 0; j < 4; ++j) {
    const int grow = (wave * 4 + j) * 8 + rl0;
    pa[j] = A + (size_t)grow * lda + cu;
    pb[j] = B + (size_t)grow * ldb + cu;
  }

#define ST_A8(SLOT, TT)                                                             \
  { _Pragma("unroll")                                                               \
    for (int j = 0; j < 4; ++j)                                                     \
      async_ld16(pa[j] + (size_t)(TT) * 64,                                         \
                 lsA + (SLOT) * 16384 + (wave * 4 + j) * 512 + lane * 8); }
#define ST_B8(SLOT, TT)                                                             \
  { _Pragma("unroll")                                                               \
    for (int j = 0; j < 4; ++j)                                                     \
      async_ld16(pb[j] + (size_t)(TT) * 64,                                         \
                 lsB + (SLOT) * 16384 + (wave * 4 + j) * 512 + lane * 8); }

  bf16x8 af03k0[4], af03k1[4], af47k0[4], af47k1[4], bfk0[4], bfk1[4];

  // prologue: A(0),B(0)->s0; B(1)->s1; VMC own-wave; BAR chip-wide; THEN read.
  ST_A8(0, 0);
  ST_B8(0, 0);
  ST_B8(1, 1);
  VMC(4);
  BAR;
#pragma unroll
  for (int mi = 0; mi < 4; ++mi) af03k0[mi] = *(const bf16x8*)(aB0 + mi * 1024);
#pragma unroll
  for (int ni = 0; ni < 4; ++ni) bfk0[ni]   = *(const bf16x8*)(bB0 + ni * 1024);

  for (int t = 0; t < NT; ++t) {
    const int sA = (t & 1) * 16384;
    const int sB = (t & 1) * 16384;

    // ---- P1: MFMA mi0-3 kk0 ----
#pragma unroll
    for (int mi = 0; mi < 4; ++mi) af03k1[mi] = *(const bf16x8*)(aB1 + sA + mi * 1024);
#pragma unroll
    for (int ni = 0; ni < 4; ++ni) bfk1[ni]   = *(const bf16x8*)(bB1 + sB + ni * 1024);
    if (t + 1 < NT) ST_A8((t + 1) & 1, t + 1);
    __builtin_amdgcn_s_setprio(1);
#pragma unroll
    for (int mi = 0; mi < 4; ++mi)
#pragma unroll
      for (int ni = 0; ni < 4; ++ni)
        acc[mi][ni] = __builtin_amdgcn_mfma_f32_16x16x32_bf16(
            af03k0[mi], bfk0[ni], acc[mi][ni], 0, 0, 0);
    __builtin_amdgcn_s_setprio(0);
    BAR;

    // ---- P2: MFMA mi0-3 kk1 ----
#pragma unroll
    for (int mi = 0; mi < 4; ++mi) af47k0[mi] = *(const bf16x8*)(aB0 + sA + 4096 + mi * 1024);
    __builtin_amdgcn_s_setprio(1);
#pragma unroll
    for (int mi = 0; mi < 4; ++mi)
#pragma unroll
      for (int ni = 0; ni < 4; ++ni)
        acc[mi][ni] = __builtin_amdgcn_mfma_f32_16x16x32_bf16(
            af03k1[mi], bfk1[ni], acc[mi][ni], 0, 0, 0);
    __builtin_amdgcn_s_setprio(0);
    BAR;

    // ---- P3: MFMA mi4-7 kk0 ----
#pragma unroll
    for (int mi = 0; mi < 4; ++mi) af47k1[mi] = *(const bf16x8*)(aB1 + sA + 4096 + mi * 1024);
    if (t + 2 < NT) ST_B8(t & 1, t + 2);
    __builtin_amdgcn_s_setprio(1);
#pragma unroll
    for (int mi = 0; mi < 4; ++mi)
#pragma unroll
      for (int ni = 0; ni < 4; ++ni)
        acc[4 + mi][ni] = __builtin_amdgcn_mfma_f32_16x16x32_bf16(
            af47k0[mi], bfk0[ni], acc[4 + mi][ni], 0, 0, 0);
    __builtin_amdgcn_s_setprio(0);
    if (t + 2 < NT) VMC(4); else VMC(0);
    BAR;

    // ---- P4: MFMA mi4-7 kk1 ----
    if (t + 1 < NT) {
      const int sA2 = ((t + 1) & 1) * 16384;
      const int sB2 = ((t + 1) & 1) * 16384;
#pragma unroll
      for (int mi = 0; mi < 4; ++mi) af03k0[mi] = *(const bf16x8*)(aB0 + sA2 + mi * 1024);
#pragma unroll
      for (int ni = 0; ni < 4; ++ni) bfk0[ni]   = *(const bf16x8*)(bB0 + sB2 + ni * 1024);
    }
    __builtin_amdgcn_s_setprio(1);
#pragma unroll
    for (int mi = 0; mi < 4; ++mi)
#pragma unroll
      for (int ni = 0; ni < 4; ++ni)
        acc[4 + mi][ni] = __builtin_amdgcn_mfma_f32_16x16x32_bf16(
            af47k1[mi], bfk1[ni], acc[4 + mi][ni], 0, 0, 0);
    __builtin_amdgcn_s_setprio(0);
    BAR;
  }
#undef ST_A8
#undef ST_B8
}

// ==================== 4-wave 128x128 pipelined core, 3-slot (pv) ====================
// 4 waves (2M x 2N), per-wave 64x64, BK=64, NT EVEN >= 2.
// LDS: lsA/lsB 3 slots x 8192 shorts (96 KB). Tile t lives in slot t%3.
// Bodies (1 barrier each):
//  P_A(t): rd b23(t)[4]@slot t%3; stage A(t+2)->slot (t+2)%3;
//          MFMA n0,n1 (af(t),b01(t)); vmcnt(4|0); BAR.
//  P_B(t): rd af(t+1)[8]+b01(t+1)[4]@slot (t+1)%3; stage B(t+2)->slot (t+2)%3;
//          MFMA n2,n3 (af(t),b23(t)); vmcnt(4|0); BAR.
// Hazards: slot (t+2)%3 = (t-1)%3 last consumed at P_B(t-1) = body before
// P_A(t). Read coverage: A(t+2) staged P_A(t), read P_B(t+1) (3 bodies);
// B(t+2) staged P_B(t), read P_B(t+1)/P_A(t+2) (2-3 bodies). vmcnt(4)/body:
// at P_A end newest 4 = A(t+2) => B(t+1) landed; at P_B end newest 4 =
// B(t+2) => A(t+2) landed. Prologue: VMC(8) -> BAR -> read (chip-wide).
__device__ __forceinline__ void gemm4p3(
    const short* __restrict__ A, const short* __restrict__ B,
    int lda, int ldb, int NT,
    short* __restrict__ lsA, short* __restrict__ lsB,
    f32x4 (&acc)[4][4])
{
  const int tid  = threadIdx.x;
  const int lane = tid & 63;
  const int wave = tid >> 6;               // 0..3
  const int wM   = wave >> 1;
  const int wN   = wave & 1;
  const int quad = lane >> 4;
  const int l15  = lane & 15;
  const int key  = l15 & 7;
  const int uk0  = (quad ^ key) * 8;
  const int uk1  = ((4 ^ quad) ^ key) * 8;
  const short* aR0 = lsA + (wM * 64 + l15) * 64 + uk0;
  const short* aR1 = lsA + (wM * 64 + l15) * 64 + uk1;
  const short* bR0 = lsB + (wN * 64 + l15) * 64 + uk0;
  const short* bR1 = lsB + (wN * 64 + l15) * 64 + uk1;
  const int rl0 = lane >> 3;
  const int cu  = ((lane & 7) ^ rl0) * 8;
  const short* pa[2][2];
  const short* pb[2][2];
#pragma unroll
  for (int u = 0; u < 2; ++u)
#pragma unroll
    for (int j = 0; j < 2; ++j) {
      pa[u][j] = A + (size_t)(u * 64 + (wave + 4 * j) * 8 + rl0) * lda + cu;
      pb[u][j] = B + (size_t)(u * 64 + (wave + 4 * j) * 8 + rl0) * ldb + cu;
    }

#define S4A(SLOT, TT)                                                               \
  { _Pragma("unroll")                                                               \
    for (int u = 0; u < 2; ++u)                                                     \
      _Pragma("unroll")                                                             \
      for (int j = 0; j < 2; ++j)                                                   \
        async_ld16(pa[u][j] + (size_t)(TT) * 64,                                    \
                   lsA + (SLOT) * 8192 + u * 4096 + (wave + 4 * j) * 512 + lane * 8); }
#define S4B(SLOT, TT)                                                               \
  { _Pragma("unroll")                                                               \
    for (int u = 0; u < 2; ++u)                                                     \
      _Pragma("unroll")                                                             \
      for (int j = 0; j < 2; ++j)                                                   \
        async_ld16(pb[u][j] + (size_t)(TT) * 64,                                    \
                   lsB + (SLOT) * 8192 + u * 4096 + (wave + 4 * j) * 512 + lane * 8); }

  bf16x8 afA[4][2], afB[4][2], b01A[2][2], b01B[2][2], b23[2][2];

#define RD_AF(DST, SLOT)                                                            \
  { _Pragma("unroll")                                                               \
    for (int i = 0; i < 4; ++i) {                                                   \
      DST[i][0] = *(const bf16x8*)(aR0 + (SLOT) * 8192 + i * 1024);                 \
      DST[i][1] = *(const bf16x8*)(aR1 + (SLOT) * 8192 + i * 1024);                 \
    } }
#define RD_B01(DST, SLOT)                                                           \
  { _Pragma("unroll")                                                               \
    for (int n = 0; n < 2; ++n) {                                                   \
      DST[n][0] = *(const bf16x8*)(bR0 + (SLOT) * 8192 + n * 1024);                 \
      DST[n][1] = *(const bf16x8*)(bR1 + (SLOT) * 8192 + n * 1024);                 \
    } }
#define RD_B23(SLOT)                                                                \
  { _Pragma("unroll")                                                               \
    for (int n = 0; n < 2; ++n) {                                                   \
      b23[n][0] = *(const bf16x8*)(bR0 + (SLOT) * 8192 + (2 + n) * 1024);           \
      b23[n][1] = *(const bf16x8*)(bR1 + (SLOT) * 8192 + (2 + n) * 1024);           \
    } }
#define MFLO(AF, B01)                                                               \
  { __builtin_amdgcn_s_setprio(1);                                                  \
    _Pragma("unroll")                                                               \
    for (int kk = 0; kk < 2; ++kk)                                                  \
      _Pragma("unroll")                                                             \
      for (int i = 0; i < 4; ++i)                                                   \
        _Pragma("unroll")                                                           \
        for (int n = 0; n < 2; ++n)                                                 \
          acc[i][n] = __builtin_amdgcn_mfma_f32_16x16x32_bf16(                      \
              AF[i][kk], B01[n][kk], acc[i][n], 0, 0, 0);                           \
    __builtin_amdgcn_s_setprio(0); }
#define MFHI(AF)                                                                    \
  { __builtin_amdgcn_s_setprio(1);                                                  \
    _Pragma("unroll")                                                               \
    for (int kk = 0; kk < 2; ++kk)                                                  \
      _Pragma("unroll")                                                             \
      for (int i = 0; i < 4; ++i)                                                   \
        _Pragma("unroll")                                                           \
        for (int n = 0; n < 2; ++n)                                                 \
          acc[i][2 + n] = __builtin_amdgcn_mfma_f32_16x16x32_bf16(                  \
              AF[i][kk], b23[n][kk], acc[i][2 + n], 0, 0, 0);                       \
    __builtin_amdgcn_s_setprio(0); }

  // prologue: tiles 0,1 -> slots 0,1; VMC(8) own-wave (A0,B0); BAR; read.
  S4A(0, 0); S4B(0, 0); S4A(1, 1); S4B(1, 1);
  VMC(8);
  BAR;
  RD_AF(afA, 0);
  RD_B01(b01A, 0);

  int s0 = 0;   // tp % 3
  for (int tp = 0; tp < NT; tp += 2) {
    int s1 = s0 + 1; if (s1 == 3) s1 = 0;   // (tp+1)%3
    int s2 = s1 + 1; if (s2 == 3) s2 = 0;   // (tp+2)%3
    const int s3 = s0;                       // (tp+3)%3
    const bool g2 = (tp + 2 < NT);
    const bool g3 = (tp + 3 < NT);

    // P_A(even)
    RD_B23(s0);
    if (g2) S4A(s2, tp + 2);
    MFLO(afA, b01A);
    if (g2) VMC(4); else VMC(0);
    BAR;
    // P_B(even)
    RD_AF(afB, s1);
    RD_B01(b01B, s1);
    if (g2) S4B(s2, tp + 2);
    MFHI(afA);
    if (g2) VMC(4); else VMC(0);
    BAR;
    // P_A(odd)
    RD_B23(s1);
    if (g3) S4A(s3, tp + 3);
    MFLO(afB, b01B);
    if (g3) VMC(4); else VMC(0);
    BAR;
    // P_B(odd)
    if (g2) { RD_AF(afA, s2); RD_B01(b01A, s2); }
    if (g3) S4B(s3, tp + 3);
    MFHI(afB);
    if (g3) VMC(4); else VMC(0);
    BAR;

    s0 = s2;
  }
#undef S4A
#undef S4B
#undef RD_AF
#undef RD_B01
#undef RD_B23
#undef MFLO
#undef MFHI
}

// ---------------- converts ----------------

__global__ __launch_bounds__(256) void k_convX(const float* __restrict__ x,
                                               short* __restrict__ y) {
  const size_t i = ((size_t)blockIdx.x * 256 + threadIdx.x) * 4;
  const float4 v = *(const float4*)(x + i);
  s16x4 o;
  o[0] = f2bf(v.x); o[1] = f2bf(v.y); o[2] = f2bf(v.z); o[3] = f2bf(v.w);
  *(s16x4*)(y + i) = o;
}

// transpose 1024x1024 W[i][c] -> bf16 Wt[c][i], 32x32 LDS tiles
__global__ __launch_bounds__(256) void k_convWt(const float* __restrict__ Wq,
                                                const float* __restrict__ Wk,
                                                const float* __restrict__ Wv,
                                                short* __restrict__ Wtq,
                                                short* __restrict__ Wtk,
                                                short* __restrict__ Wtv) {
  const float* W = (blockIdx.z == 0) ? Wq : (blockIdx.z == 1) ? Wk : Wv;
  short* Wt      = (blockIdx.z == 0) ? Wtq : (blockIdx.z == 1) ? Wtk : Wtv;
  __shared__ float t[32][33];
  const int tx = threadIdx.x & 31;
  const int ty = threadIdx.x >> 5;
  const int bc = blockIdx.x * 32;
  const int bi = blockIdx.y * 32;
#pragma unroll
  for (int j = 0; j < 32; j += 8)
    t[ty + j][tx] = W[(size_t)(bi + ty + j) * 1024 + bc + tx];
  __syncthreads();
#pragma unroll
  for (int j = 0; j < 32; j += 8)
    Wt[(size_t)(bc + ty + j) * 1024 + bi + tx] = f2bf(t[tx][ty + j]);
}

// ---------------- GEMMs ----------------

// Fused projections, 256x256 tiles (gemm8p), 384 blocks @1/CU.
// y=0: Q, y=1: K (M=8192: m=bx>>2; N=1024: n=bx&3)
// y=2: V^T      (M=1024: m=bx>>5; N=8192: n=bx&31)
__global__ __launch_bounds__(512, 1) void k_proj(
    const short* __restrict__ Xb, const short* __restrict__ Wtq,
    const short* __restrict__ Wtk, const short* __restrict__ Wtv,
    short* __restrict__ Qb, short* __restrict__ Kb, short* __restrict__ Vt) {
  __shared__ short lsA[2 * 16384];   // 64 KB
  __shared__ short lsB[2 * 16384];   // 64 KB (128 KB total)
  f32x4 acc[8][4];
#pragma unroll
  for (int i = 0; i < 8; ++i)
#pragma unroll
    for (int j = 0; j < 4; ++j) acc[i][j] = 0.f;

  const int z  = blockIdx.y;
  const int bx = blockIdx.x;
  const short* Ab;
  const short* Bb;
  int m, n;
  if (z < 2) {
    m = bx >> 2; n = bx & 3;
    Ab = Xb + (size_t)m * 256 * 1024;
    Bb = (z ? Wtk : Wtq) + (size_t)n * 256 * 1024;
  } else {
    m = bx >> 5; n = bx & 31;
    Ab = Wtv + (size_t)m * 256 * 1024;
    Bb = Xb + (size_t)n * 256 * 1024;
  }
  gemm8p(Ab, Bb, 1024, 1024, 16, lsA, lsB, acc);

  const int lane = threadIdx.x & 63, wave = threadIdx.x >> 6;
  const int wM = wave >> 2, wN = wave & 3;
  const int quad = lane >> 4, l15 = lane & 15;
  if (z < 2) {
    short* O = z ? Kb : Qb;
#pragma unroll
    for (int mi = 0; mi < 8; ++mi)
#pragma unroll
      for (int ni = 0; ni < 4; ++ni)
#pragma unroll
        for (int r = 0; r < 4; ++r) {
          const int row = m * 256 + wM * 128 + mi * 16 + quad * 4 + r;
          const int col = n * 256 + wN * 64 + ni * 16 + l15;
          O[(size_t)row * 1024 + col] = f2bf(acc[mi][ni][r]);
        }
  } else {
#pragma unroll
    for (int mi = 0; mi < 8; ++mi)
#pragma unroll
      for (int ni = 0; ni < 4; ++ni)
#pragma unroll
        for (int r = 0; r < 4; ++r) {
          const int crow = m * 256 + wM * 128 + mi * 16 + quad * 4 + r;
          const int t8   = n * 256 + wN * 64 + ni * 16 + l15;
          const int b = t8 >> 12, tt = t8 & 4095;
          Vt[(size_t)b * C_DIM * T_SEQ + (size_t)crow * T_SEQ + tt] =
              f2bf(acc[mi][ni][r]);
        }
  }
}

// Scores: 256x256 tiles (gemm8p), keep nn >= mm (256-granular): 136/batch,
// 272 blocks @1/CU. A = Q nn-tile, B = K mm-tile; per-element mask+decay.
__global__ __launch_bounds__(512, 1) void k_scores(const short* __restrict__ Qb,
                                                   const short* __restrict__ Kb,
                                                   short* __restrict__ P) {
  __shared__ short lsA[2 * 16384];   // 64 KB
  __shared__ short lsB[2 * 16384];   // 64 KB
  f32x4 acc[8][4];
#pragma unroll
  for (int i = 0; i < 8; ++i)
#pragma unroll
    for (int j = 0; j < 4; ++j) acc[i][j] = 0.f;

  int id = blockIdx.x, mm = 0;
  while (id >= 16 - mm) { id -= 16 - mm; ++mm; }
  const int nn = mm + id;

  const size_t b = blockIdx.y;
  const short* Ab = Qb + b * T_SEQ * C_DIM + (size_t)nn * 256 * 1024;
  const short* Bb = Kb + b * T_SEQ * C_DIM + (size_t)mm * 256 * 1024;
  gemm8p(Ab, Bb, 1024, 1024, 16, lsA, lsB, acc);

  short* Pb = P + b * (size_t)T_SEQ * T_SEQ;
  const int lane = threadIdx.x & 63, wave = threadIdx.x >> 6;
  const int wM = wave >> 2, wN = wave & 3;
  const int quad = lane >> 4, l15 = lane & 15;
#pragma unroll
  for (int mi = 0; mi < 8; ++mi)
#pragma unroll
    for (int ni = 0; ni < 4; ++ni)
#pragma unroll
      for (int r = 0; r < 4; ++r) {
        const int n = nn * 256 + wM * 128 + mi * 16 + quad * 4 + r;
        const int m = mm * 256 + wN * 64 + ni * 16 + l15;
        float v = 0.f;
        if (n >= m) v = acc[mi][ni][r] * exp2f((float)(n - m) * L2G);
        Pb[(size_t)n * T_SEQ + m] = f2bf(v);
      }
}

// PV: out[b][i][t] = Vt[b][i][:] . P[b][t][:], 128-wide t-columns.
// Col c (t in [128c, 128c+128)) needs NT = 2c+2 K-tiles (P beyond its
// diagonal tile is mask-written zero by scores; read region verified inside
// the 256-granular written triangle). Pair (p, 31-p): every block runs
// exactly 66 K-tiles of a 128(i)x128(t) tile (two gemm4p3 calls).
// 16 pairs x 8 i-tiles x 2 b = 256 equal blocks @1/CU; plain f32 stores.
__global__ __launch_bounds__(256, 1) void k_pv(const short* __restrict__ Vt,
                                               const short* __restrict__ P,
                                               float* __restrict__ out) {
  __shared__ short lsA[3 * 8192];   // 48 KB
  __shared__ short lsB[3 * 8192];   // 48 KB (96 KB total)
  const int p  = blockIdx.x;        // pair id 0..15
  const int iy = blockIdx.y;        // i-tile (128 wide)
  const size_t b = blockIdx.z;

  const short* Ab = Vt + b * (size_t)C_DIM * T_SEQ + (size_t)iy * 128 * T_SEQ;
  const short* Pb = P + b * (size_t)T_SEQ * T_SEQ;
  float* Ob = out + b * (size_t)C_DIM * T_SEQ;

  const int lane = threadIdx.x & 63, wave = threadIdx.x >> 6;
  const int wM = wave >> 1, wN = wave & 1;
  const int quad = lane >> 4, l15 = lane & 15;

  const int cols[2] = { 31 - p, p };    // long column first
#pragma unroll
  for (int cc = 0; cc < 2; ++cc) {
    const int c = cols[cc];
    f32x4 acc[4][4];
#pragma unroll
    for (int i = 0; i < 4; ++i)
#pragma unroll
      for (int j = 0; j < 4; ++j) acc[i][j] = 0.f;
    gemm4p3(Ab, Pb + (size_t)c * 128 * T_SEQ, T_SEQ, T_SEQ, 2 * c + 2,
            lsA, lsB, acc);
#pragma unroll
    for (int mi = 0; mi < 4; ++mi)
#pragma unroll
      for (int ni = 0; ni < 4; ++ni)
#pragma unroll
        for (int r = 0; r < 4; ++r) {
          const int irow = iy * 128 + wM * 64 + mi * 16 + quad * 4 + r;
          const int tcol = c * 128 + wN * 64 + ni * 16 + l15;
          Ob[(size_t)irow * T_SEQ + tcol] = acc[mi][ni][r];
        }
  }
}

// ---------------- launch ----------------

extern "C" void kernel_launch(void* const* d_in, const int* in_sizes, int n_in,
                              void* d_out, int out_size, void* d_ws, size_t ws_size,
                              hipStream_t stream) {
  const float* X  = (const float*)d_in[0];
  // d_in[1] att_mask (unused), d_in[2] S_n (zeros, passthrough)
  const float* Wq = (const float*)d_in[3];
  const float* Wk = (const float*)d_in[4];
  const float* Wv = (const float*)d_in[5];
  float* out = (float*)d_out;

  char* ws = (char*)d_ws;
  short* Xb  = (short*)(ws);                 // 16,777,216  X bf16 [B*T, I]
  short* Wtq = (short*)(ws + 16777216);      //  2,097,152  Wq^T bf16 [c][i]
  short* Wtk = (short*)(ws + 18874368);      //  2,097,152
  short* Wtv = (short*)(ws + 20971520);      //  2,097,152
  short* Qb  = (short*)(ws + 23068672);      // 16,777,216  [B*T, C]
  short* Kb  = (short*)(ws + 39845888);      // 16,777,216
  short* Vt  = (short*)(ws + 56623104);      // 16,777,216  [B, I, T]
  short* P   = (short*)(ws + 73400320);      // 67,108,864  [B, T, T]

  // main out region fully written by k_pv plain stores; zero only S_n tail.
  const size_t mainN = (size_t)2 * T_SEQ * C_DIM;   // 8,388,608 floats
  hipMemsetAsync((char*)d_out + mainN * 4, 0,
                 ((size_t)out_size - mainN) * 4, stream);

  k_convX  <<<dim3(8192),       dim3(256), 0, stream>>>(X, Xb);
  k_convWt <<<dim3(32, 32, 3),  dim3(256), 0, stream>>>(Wq, Wk, Wv, Wtq, Wtk, Wtv);
  k_proj   <<<dim3(128, 3),     dim3(512), 0, stream>>>(Xb, Wtq, Wtk, Wtv, Qb, Kb, Vt);
  k_scores <<<dim3(136, 2),     dim3(512), 0, stream>>>(Qb, Kb, P);
  k_pv     <<<dim3(16, 8, 2),   dim3(256), 0, stream>>>(Vt, P, out);
}

// Round 9
// 269.346 us; speedup vs baseline: 1.0643x; 1.0643x over previous
//
#include <hip/hip_runtime.h>
#include <cstdint>
#include <cstddef>

// COINBlock (RetNet-style retention, parallel form) on MI355X.
// Shapes: B=2, T=4096, I=C=1024.
//   Q = X@Wq, K = X@Wk, V = X@Wv            (bf16 MFMA, fp32 accum)
//   P = (Q K^T) * D,  D[n,m] = g^(n-m)*[n>=m]   (lower-tri tiles only)
//   out^T[i][t] = sum_m V^T[i][m] * P[t][m]     (output IS the transposed layout)
// All GEMMs are gemm_bt form: C[m][n] = sum_k A[m][k]*B[n][k], k-contiguous.
//
// R16 post-mortem: pipelined reads did NOT overlap within one barrier domain:
//   body still ~1300 cyc (LDS 576 + MFMA 516 + bar). All three GEMMs ~69 us
//   (proj 1.5-round makespan=2, scores 272/256=2 rounds, pv 132x1260).
// R17: gemm4p2 = gemm4p3 pipeline with A 2-slot + B 3-slot = 80 KB ->
//   2 blocks/CU (independent barrier domains; one block's LDS/VMC stalls hide
//   under the other's MFMA). Hazard audit: stage B(t+2)@P_A(t) -> slot
//   (t-1)%3 (reads lgkm-done P_A(t-1)/P_B(t-2), consumed P_B(t-1), 1 bar
//   before stage); stage A(t+2)@P_B(t) -> slot t&1 (af(t) reads lgkm-done
//   before MFLO@P_A(t), 1 bar). Coverage: af(t+1)@P_B(t) forced by
//   VMC(4)@P_A(t) [queue A(t+1),B(t+2)=8 -> wait 4]; b01(t+2)@P_B(t+1)
//   forced by VMC(4)@P_B(t). Prologue: stage 16 -> VMC(8) -> BAR -> read.
//   proj: 128^2 tiles, 1536 blocks = 3.0 exact rounds @2/CU.
//   scores: 128^2, 528x2 = 1056 blocks @2/CU = 2.06 rounds (R12 mapping).
//   pv: UNCHANGED (gemm4p3, passed) to cap correctness risk.

using bf16x8 = __attribute__((ext_vector_type(8))) short;
using s16x4  = __attribute__((ext_vector_type(4))) short;
using f32x4  = __attribute__((ext_vector_type(4))) float;

#define T_SEQ 4096
#define C_DIM 1024

static constexpr float L2G = -0.0144995697f; // log2(0.99)

__device__ __forceinline__ short f2bf(float f) {
  unsigned u = __builtin_bit_cast(unsigned, f);
  u += 0x7FFFu + ((u >> 16) & 1u);   // round-to-nearest-even
  return (short)(u >> 16);
}

// async 16B/lane global->LDS (dest = wave-uniform base + lane*16).
__device__ __forceinline__ void async_ld16(const short* g, const short* l) {
  __builtin_amdgcn_global_load_lds(
      (const __attribute__((address_space(1))) unsigned int*)(uintptr_t)g,
      (__attribute__((address_space(3))) unsigned int*)(unsigned)(uintptr_t)l,
      16, 0, 0);
}

#define FENCE asm volatile("" ::: "memory")
#define BAR   do { FENCE; __builtin_amdgcn_s_barrier(); FENCE; } while (0)
#define VMC(N) asm volatile("s_waitcnt vmcnt(" #N ")" ::: "memory")

// Common 4-wave geometry helpers (128-row A tile, 128-col B tile, BK=64).
// Swizzle: LDS[R][u8] = G[R][u8 ^ (R&7)] (8-short units); readers XOR row key.

// ==================== 4-wave 128x128 pipelined core, A2+B3 slots (80 KB) ====================
// 4 waves (2M x 2N), per-wave 64x64, BK=64, NT EVEN >= 2. 2 blocks/CU.
// lsA: 2 slots x 8192 sh (32 KB); lsB: 3 slots x 8192 sh (48 KB).
// A tile t -> slot t&1; B tile t -> slot t%3.
// Bodies (1 barrier each; MFMA operands read >=1 body earlier):
//  P_A(t): rd b23(t)@B-slot t%3; stage B(t+2)->B-slot (t+2)%3;
//          MFLO(af(t),b01(t)); VMC(4|0); BAR.
//  P_B(t): rd af(t+1)@A-slot (t+1)&1 + b01(t+1)@B-slot (t+1)%3;
//          stage A(t+2)->A-slot t&1; MFHI(af(t),b23(t)); VMC(4|0); BAR.
__device__ __forceinline__ void gemm4p2(
    const short* __restrict__ A, const short* __restrict__ B,
    int lda, int ldb, int NT,
    short* __restrict__ lsA, short* __restrict__ lsB,
    f32x4 (&acc)[4][4])
{
  const int tid  = threadIdx.x;
  const int lane = tid & 63;
  const int wave = tid >> 6;               // 0..3
  const int wM   = wave >> 1;
  const int wN   = wave & 1;
  const int quad = lane >> 4;
  const int l15  = lane & 15;
  const int key  = l15 & 7;
  const int uk0  = (quad ^ key) * 8;
  const int uk1  = ((4 ^ quad) ^ key) * 8;
  const short* aR0 = lsA + (wM * 64 + l15) * 64 + uk0;
  const short* aR1 = lsA + (wM * 64 + l15) * 64 + uk1;
  const short* bR0 = lsB + (wN * 64 + l15) * 64 + uk0;
  const short* bR1 = lsB + (wN * 64 + l15) * 64 + uk1;
  const int rl0 = lane >> 3;
  const int cu  = ((lane & 7) ^ rl0) * 8;
  const short* pa[2][2];
  const short* pb[2][2];
#pragma unroll
  for (int u = 0; u < 2; ++u)
#pragma unroll
    for (int j = 0; j < 2; ++j) {
      pa[u][j] = A + (size_t)(u * 64 + (wave + 4 * j) * 8 + rl0) * lda + cu;
      pb[u][j] = B + (size_t)(u * 64 + (wave + 4 * j) * 8 + rl0) * ldb + cu;
    }

#define S4A(SLOT, TT)                                                               \
  { _Pragma("unroll")                                                               \
    for (int u = 0; u < 2; ++u)                                                     \
      _Pragma("unroll")                                                             \
      for (int j = 0; j < 2; ++j)                                                   \
        async_ld16(pa[u][j] + (size_t)(TT) * 64,                                    \
                   lsA + (SLOT) * 8192 + u * 4096 + (wave + 4 * j) * 512 + lane * 8); }
#define S4B(SLOT, TT)                                                               \
  { _Pragma("unroll")                                                               \
    for (int u = 0; u < 2; ++u)                                                     \
      _Pragma("unroll")                                                             \
      for (int j = 0; j < 2; ++j)                                                   \
        async_ld16(pb[u][j] + (size_t)(TT) * 64,                                    \
                   lsB + (SLOT) * 8192 + u * 4096 + (wave + 4 * j) * 512 + lane * 8); }

  bf16x8 afA[4][2], afB[4][2], b01A[2][2], b01B[2][2], b23[2][2];

#define RD_AF(DST, SLOT)                                                            \
  { _Pragma("unroll")                                                               \
    for (int i = 0; i < 4; ++i) {                                                   \
      DST[i][0] = *(const bf16x8*)(aR0 + (SLOT) * 8192 + i * 1024);                 \
      DST[i][1] = *(const bf16x8*)(aR1 + (SLOT) * 8192 + i * 1024);                 \
    } }
#define RD_B01(DST, SLOT)                                                           \
  { _Pragma("unroll")                                                               \
    for (int n = 0; n < 2; ++n) {                                                   \
      DST[n][0] = *(const bf16x8*)(bR0 + (SLOT) * 8192 + n * 1024);                 \
      DST[n][1] = *(const bf16x8*)(bR1 + (SLOT) * 8192 + n * 1024);                 \
    } }
#define RD_B23(SLOT)                                                                \
  { _Pragma("unroll")                                                               \
    for (int n = 0; n < 2; ++n) {                                                   \
      b23[n][0] = *(const bf16x8*)(bR0 + (SLOT) * 8192 + (2 + n) * 1024);           \
      b23[n][1] = *(const bf16x8*)(bR1 + (SLOT) * 8192 + (2 + n) * 1024);           \
    } }
#define MFLO(AF, B01)                                                               \
  { __builtin_amdgcn_s_setprio(1);                                                  \
    _Pragma("unroll")                                                               \
    for (int kk = 0; kk < 2; ++kk)                                                  \
      _Pragma("unroll")                                                             \
      for (int i = 0; i < 4; ++i)                                                   \
        _Pragma("unroll")                                                           \
        for (int n = 0; n < 2; ++n)                                                 \
          acc[i][n] = __builtin_amdgcn_mfma_f32_16x16x32_bf16(                      \
              AF[i][kk], B01[n][kk], acc[i][n], 0, 0, 0);                           \
    __builtin_amdgcn_s_setprio(0); }
#define MFHI(AF)                                                                    \
  { __builtin_amdgcn_s_setprio(1);                                                  \
    _Pragma("unroll")                                                               \
    for (int kk = 0; kk < 2; ++kk)                                                  \
      _Pragma("unroll")                                                             \
      for (int i = 0; i < 4; ++i)                                                   \
        _Pragma("unroll")                                                           \
        for (int n = 0; n < 2; ++n)                                                 \
          acc[i][2 + n] = __builtin_amdgcn_mfma_f32_16x16x32_bf16(                  \
              AF[i][kk], b23[n][kk], acc[i][2 + n], 0, 0, 0);                       \
    __builtin_amdgcn_s_setprio(0); }

  // prologue: A(0)->s0,B(0)->s0,A(1)->s1,B(1)->s1; VMC(8) (A0,B0 landed);
  // BAR (chip-wide); read tile0 operands.
  S4A(0, 0); S4B(0, 0); S4A(1, 1); S4B(1, 1);
  VMC(8);
  BAR;
  RD_AF(afA, 0);
  RD_B01(b01A, 0);

  int s0 = 0;   // tp % 3 (B slots)
  for (int tp = 0; tp < NT; tp += 2) {
    int s1 = s0 + 1; if (s1 == 3) s1 = 0;   // (tp+1)%3
    int s2 = s1 + 1; if (s2 == 3) s2 = 0;   // (tp+2)%3
    const int s3 = s0;                       // (tp+3)%3
    const bool g2 = (tp + 2 < NT);
    const bool g3 = (tp + 3 < NT);

    // P_A(even): tile tp (A slot 0)
    RD_B23(s0);
    if (g2) S4B(s2, tp + 2);
    MFLO(afA, b01A);
    if (g2) VMC(4); else VMC(0);
    BAR;
    // P_B(even)
    RD_AF(afB, 1);
    RD_B01(b01B, s1);
    if (g2) S4A(0, tp + 2);
    MFHI(afA);
    if (g2) VMC(4); else VMC(0);
    BAR;
    // P_A(odd): tile tp+1 (A slot 1)
    RD_B23(s1);
    if (g3) S4B(s3, tp + 3);
    MFLO(afB, b01B);
    if (g3) VMC(4); else VMC(0);
    BAR;
    // P_B(odd)
    if (g2) { RD_AF(afA, 0); RD_B01(b01A, s2); }
    if (g3) S4A(1, tp + 3);
    MFHI(afB);
    if (g3) VMC(4); else VMC(0);
    BAR;

    s0 = s2;
  }
#undef S4A
#undef S4B
#undef RD_AF
#undef RD_B01
#undef RD_B23
#undef MFLO
#undef MFHI
}

// ==================== 4-wave 128x128 pipelined core, 3+3 slots (pv; R15, passed) ====================
__device__ __forceinline__ void gemm4p3(
    const short* __restrict__ A, const short* __restrict__ B,
    int lda, int ldb, int NT,
    short* __restrict__ lsA, short* __restrict__ lsB,
    f32x4 (&acc)[4][4])
{
  const int tid  = threadIdx.x;
  const int lane = tid & 63;
  const int wave = tid >> 6;               // 0..3
  const int wM   = wave >> 1;
  const int wN   = wave & 1;
  const int quad = lane >> 4;
  const int l15  = lane & 15;
  const int key  = l15 & 7;
  const int uk0  = (quad ^ key) * 8;
  const int uk1  = ((4 ^ quad) ^ key) * 8;
  const short* aR0 = lsA + (wM * 64 + l15) * 64 + uk0;
  const short* aR1 = lsA + (wM * 64 + l15) * 64 + uk1;
  const short* bR0 = lsB + (wN * 64 + l15) * 64 + uk0;
  const short* bR1 = lsB + (wN * 64 + l15) * 64 + uk1;
  const int rl0 = lane >> 3;
  const int cu  = ((lane & 7) ^ rl0) * 8;
  const short* pa[2][2];
  const short* pb[2][2];
#pragma unroll
  for (int u = 0; u < 2; ++u)
#pragma unroll
    for (int j = 0; j < 2; ++j) {
      pa[u][j] = A + (size_t)(u * 64 + (wave + 4 * j) * 8 + rl0) * lda + cu;
      pb[u][j] = B + (size_t)(u * 64 + (wave + 4 * j) * 8 + rl0) * ldb + cu;
    }

#define S4A(SLOT, TT)                                                               \
  { _Pragma("unroll")                                                               \
    for (int u = 0; u < 2; ++u)                                                     \
      _Pragma("unroll")                                                             \
      for (int j = 0; j < 2; ++j)                                                   \
        async_ld16(pa[u][j] + (size_t)(TT) * 64,                                    \
                   lsA + (SLOT) * 8192 + u * 4096 + (wave + 4 * j) * 512 + lane * 8); }
#define S4B(SLOT, TT)                                                               \
  { _Pragma("unroll")                                                               \
    for (int u = 0; u < 2; ++u)                                                     \
      _Pragma("unroll")                                                             \
      for (int j = 0; j < 2; ++j)                                                   \
        async_ld16(pb[u][j] + (size_t)(TT) * 64,                                    \
                   lsB + (SLOT) * 8192 + u * 4096 + (wave + 4 * j) * 512 + lane * 8); }

  bf16x8 afA[4][2], afB[4][2], b01A[2][2], b01B[2][2], b23[2][2];

#define RD_AF(DST, SLOT)                                                            \
  { _Pragma("unroll")                                                               \
    for (int i = 0; i < 4; ++i) {                                                   \
      DST[i][0] = *(const bf16x8*)(aR0 + (SLOT) * 8192 + i * 1024);                 \
      DST[i][1] = *(const bf16x8*)(aR1 + (SLOT) * 8192 + i * 1024);                 \
    } }
#define RD_B01(DST, SLOT)                                                           \
  { _Pragma("unroll")                                                               \
    for (int n = 0; n < 2; ++n) {                                                   \
      DST[n][0] = *(const bf16x8*)(bR0 + (SLOT) * 8192 + n * 1024);                 \
      DST[n][1] = *(const bf16x8*)(bR1 + (SLOT) * 8192 + n * 1024);                 \
    } }
#define RD_B23(SLOT)                                                                \
  { _Pragma("unroll")                                                               \
    for (int n = 0; n < 2; ++n) {                                                   \
      b23[n][0] = *(const bf16x8*)(bR0 + (SLOT) * 8192 + (2 + n) * 1024);           \
      b23[n][1] = *(const bf16x8*)(bR1 + (SLOT) * 8192 + (2 + n) * 1024);           \
    } }
#define MFLO(AF, B01)                                                               \
  { __builtin_amdgcn_s_setprio(1);                                                  \
    _Pragma("unroll")                                                               \
    for (int kk = 0; kk < 2; ++kk)                                                  \
      _Pragma("unroll")                                                             \
      for (int i = 0; i < 4; ++i)                                                   \
        _Pragma("unroll")                                                           \
        for (int n = 0; n < 2; ++n)                                                 \
          acc[i][n] = __builtin_amdgcn_mfma_f32_16x16x32_bf16(                      \
              AF[i][kk], B01[n][kk], acc[i][n], 0, 0, 0);                           \
    __builtin_amdgcn_s_setprio(0); }
#define MFHI(AF)                                                                    \
  { __builtin_amdgcn_s_setprio(1);                                                  \
    _Pragma("unroll")                                                               \
    for (int kk = 0; kk < 2; ++kk)                                                  \
      _Pragma("unroll")                                                             \
      for (int i = 0; i < 4; ++i)                                                   \
        _Pragma("unroll")                                                           \
        for (int n = 0; n < 2; ++n)                                                 \
          acc[i][2 + n] = __builtin_amdgcn_mfma_f32_16x16x32_bf16(                  \
              AF[i][kk], b23[n][kk], acc[i][2 + n], 0, 0, 0);                       \
    __builtin_amdgcn_s_setprio(0); }

  // prologue: tiles 0,1 -> slots 0,1; VMC(8) own-wave (A0,B0); BAR; read.
  S4A(0, 0); S4B(0, 0); S4A(1, 1); S4B(1, 1);
  VMC(8);
  BAR;
  RD_AF(afA, 0);
  RD_B01(b01A, 0);

  int s0 = 0;   // tp % 3
  for (int tp = 0; tp < NT; tp += 2) {
    int s1 = s0 + 1; if (s1 == 3) s1 = 0;   // (tp+1)%3
    int s2 = s1 + 1; if (s2 == 3) s2 = 0;   // (tp+2)%3
    const int s3 = s0;                       // (tp+3)%3
    const bool g2 = (tp + 2 < NT);
    const bool g3 = (tp + 3 < NT);

    // P_A(even)
    RD_B23(s0);
    if (g2) S4A(s2, tp + 2);
    MFLO(afA, b01A);
    if (g2) VMC(4); else VMC(0);
    BAR;
    // P_B(even)
    RD_AF(afB, s1);
    RD_B01(b01B, s1);
    if (g2) S4B(s2, tp + 2);
    MFHI(afA);
    if (g2) VMC(4); else VMC(0);
    BAR;
    // P_A(odd)
    RD_B23(s1);
    if (g3) S4A(s3, tp + 3);
    MFLO(afB, b01B);
    if (g3) VMC(4); else VMC(0);
    BAR;
    // P_B(odd)
    if (g2) { RD_AF(afA, s2); RD_B01(b01A, s2); }
    if (g3) S4B(s3, tp + 3);
    MFHI(afB);
    if (g3) VMC(4); else VMC(0);
    BAR;

    s0 = s2;
  }
#undef S4A
#undef S4B
#undef RD_AF
#undef RD_B01
#undef RD_B23
#undef MFLO
#undef MFHI
}

// ---------------- converts ----------------

__global__ __launch_bounds__(256) void k_convX(const float* __restrict__ x,
                                               short* __restrict__ y) {
  const size_t i = ((size_t)blockIdx.x * 256 + threadIdx.x) * 4;
  const float4 v = *(const float4*)(x + i);
  s16x4 o;
  o[0] = f2bf(v.x); o[1] = f2bf(v.y); o[2] = f2bf(v.z); o[3] = f2bf(v.w);
  *(s16x4*)(y + i) = o;
}

// transpose 1024x1024 W[i][c] -> bf16 Wt[c][i], 32x32 LDS tiles
__global__ __launch_bounds__(256) void k_convWt(const float* __restrict__ Wq,
                                                const float* __restrict__ Wk,
                                                const float* __restrict__ Wv,
                                                short* __restrict__ Wtq,
                                                short* __restrict__ Wtk,
                                                short* __restrict__ Wtv) {
  const float* W = (blockIdx.z == 0) ? Wq : (blockIdx.z == 1) ? Wk : Wv;
  short* Wt      = (blockIdx.z == 0) ? Wtq : (blockIdx.z == 1) ? Wtk : Wtv;
  __shared__ float t[32][33];
  const int tx = threadIdx.x & 31;
  const int ty = threadIdx.x >> 5;
  const int bc = blockIdx.x * 32;
  const int bi = blockIdx.y * 32;
#pragma unroll
  for (int j = 0; j < 32; j += 8)
    t[ty + j][tx] = W[(size_t)(bi + ty + j) * 1024 + bc + tx];
  __syncthreads();
#pragma unroll
  for (int j = 0; j < 32; j += 8)
    Wt[(size_t)(bc + ty + j) * 1024 + bi + tx] = f2bf(t[tx][ty + j]);
}

// ---------------- GEMMs ----------------

// Fused projections, 128x128 tiles (gemm4p2), 1536 blocks = 3 rounds @2/CU.
// y=0: Q, y=1: K (M=8192: m=bx>>3; N=1024: n=bx&7)
// y=2: V^T      (M=1024: m=bx>>6; N=8192: n=bx&63)
__global__ __launch_bounds__(256, 2) void k_proj(
    const short* __restrict__ Xb, const short* __restrict__ Wtq,
    const short* __restrict__ Wtk, const short* __restrict__ Wtv,
    short* __restrict__ Qb, short* __restrict__ Kb, short* __restrict__ Vt) {
  __shared__ short lsA[2 * 8192];   // 32 KB
  __shared__ short lsB[3 * 8192];   // 48 KB (80 KB total -> 2 blocks/CU)
  f32x4 acc[4][4];
#pragma unroll
  for (int i = 0; i < 4; ++i)
#pragma unroll
    for (int j = 0; j < 4; ++j) acc[i][j] = 0.f;

  const int z  = blockIdx.y;
  const int bx = blockIdx.x;
  const short* Ab;
  const short* Bb;
  int m, n;
  if (z < 2) {
    m = bx >> 3; n = bx & 7;
    Ab = Xb + (size_t)m * 128 * 1024;
    Bb = (z ? Wtk : Wtq) + (size_t)n * 128 * 1024;
  } else {
    m = bx >> 6; n = bx & 63;
    Ab = Wtv + (size_t)m * 128 * 1024;
    Bb = Xb + (size_t)n * 128 * 1024;
  }
  gemm4p2(Ab, Bb, 1024, 1024, 16, lsA, lsB, acc);

  const int lane = threadIdx.x & 63, wave = threadIdx.x >> 6;
  const int wM = wave >> 1, wN = wave & 1;
  const int quad = lane >> 4, l15 = lane & 15;
  if (z < 2) {
    short* O = z ? Kb : Qb;
#pragma unroll
    for (int mi = 0; mi < 4; ++mi)
#pragma unroll
      for (int ni = 0; ni < 4; ++ni)
#pragma unroll
        for (int r = 0; r < 4; ++r) {
          const int row = m * 128 + wM * 64 + mi * 16 + quad * 4 + r;
          const int col = n * 128 + wN * 64 + ni * 16 + l15;
          O[(size_t)row * 1024 + col] = f2bf(acc[mi][ni][r]);
        }
  } else {
#pragma unroll
    for (int mi = 0; mi < 4; ++mi)
#pragma unroll
      for (int ni = 0; ni < 4; ++ni)
#pragma unroll
        for (int r = 0; r < 4; ++r) {
          const int crow = m * 128 + wM * 64 + mi * 16 + quad * 4 + r;
          const int t8   = n * 128 + wN * 64 + ni * 16 + l15;
          const int b = t8 >> 12, tt = t8 & 4095;
          Vt[(size_t)b * C_DIM * T_SEQ + (size_t)crow * T_SEQ + tt] =
              f2bf(acc[mi][ni][r]);
        }
  }
}

// Scores: 128x128 tiles (gemm4p2), nn >= mm: 528/batch, 1056 blocks @2/CU.
__global__ __launch_bounds__(256, 2) void k_scores(const short* __restrict__ Qb,
                                                   const short* __restrict__ Kb,
                                                   short* __restrict__ P) {
  __shared__ short lsA[2 * 8192];   // 32 KB
  __shared__ short lsB[3 * 8192];   // 48 KB
  f32x4 acc[4][4];
#pragma unroll
  for (int i = 0; i < 4; ++i)
#pragma unroll
    for (int j = 0; j < 4; ++j) acc[i][j] = 0.f;

  int id = blockIdx.x, mm = 0;
  while (id >= 32 - mm) { id -= 32 - mm; ++mm; }
  const int nn = mm + id;

  const size_t b = blockIdx.y;
  const short* Ab = Qb + b * T_SEQ * C_DIM + (size_t)nn * 128 * 1024;
  const short* Bb = Kb + b * T_SEQ * C_DIM + (size_t)mm * 128 * 1024;
  gemm4p2(Ab, Bb, 1024, 1024, 16, lsA, lsB, acc);

  short* Pb = P + b * (size_t)T_SEQ * T_SEQ;
  const int lane = threadIdx.x & 63, wave = threadIdx.x >> 6;
  const int wM = wave >> 1, wN = wave & 1;
  const int quad = lane >> 4, l15 = lane & 15;
#pragma unroll
  for (int mi = 0; mi < 4; ++mi)
#pragma unroll
    for (int ni = 0; ni < 4; ++ni)
#pragma unroll
      for (int r = 0; r < 4; ++r) {
        const int n = nn * 128 + wM * 64 + mi * 16 + quad * 4 + r;
        const int m = mm * 128 + wN * 64 + ni * 16 + l15;
        float v = 0.f;
        if (n >= m) v = acc[mi][ni][r] * exp2f((float)(n - m) * L2G);
        Pb[(size_t)n * T_SEQ + m] = f2bf(v);
      }
}

// PV: out[b][i][t] = Vt[b][i][:] . P[b][t][:], 128-wide t-columns.
// Col c needs NT = 2c+2 K-tiles. Pair (p, 31-p): every block runs exactly 66
// K-tiles of a 128(i)x128(t) tile (two gemm4p3 calls). 256 equal blocks
// @1/CU; plain f32 stores. (Unchanged from R15 -- passed.)
__global__ __launch_bounds__(256, 1) void k_pv(const short* __restrict__ Vt,
                                               const short* __restrict__ P,
                                               float* __restrict__ out) {
  __shared__ short lsA[3 * 8192];   // 48 KB
  __shared__ short lsB[3 * 8192];   // 48 KB (96 KB total)
  const int p  = blockIdx.x;        // pair id 0..15
  const int iy = blockIdx.y;        // i-tile (128 wide)
  const size_t b = blockIdx.z;

  const short* Ab = Vt + b * (size_t)C_DIM * T_SEQ + (size_t)iy * 128 * T_SEQ;
  const short* Pb = P + b * (size_t)T_SEQ * T_SEQ;
  float* Ob = out + b * (size_t)C_DIM * T_SEQ;

  const int lane = threadIdx.x & 63, wave = threadIdx.x >> 6;
  const int wM = wave >> 1, wN = wave & 1;
  const int quad = lane >> 4, l15 = lane & 15;

  const int cols[2] = { 31 - p, p };    // long column first
#pragma unroll
  for (int cc = 0; cc < 2; ++cc) {
    const int c = cols[cc];
    f32x4 acc[4][4];
#pragma unroll
    for (int i = 0; i < 4; ++i)
#pragma unroll
      for (int j = 0; j < 4; ++j) acc[i][j] = 0.f;
    gemm4p3(Ab, Pb + (size_t)c * 128 * T_SEQ, T_SEQ, T_SEQ, 2 * c + 2,
            lsA, lsB, acc);
#pragma unroll
    for (int mi = 0; mi < 4; ++mi)
#pragma unroll
      for (int ni = 0; ni < 4; ++ni)
#pragma unroll
        for (int r = 0; r < 4; ++r) {
          const int irow = iy * 128 + wM * 64 + mi * 16 + quad * 4 + r;
          const int tcol = c * 128 + wN * 64 + ni * 16 + l15;
          Ob[(size_t)irow * T_SEQ + tcol] = acc[mi][ni][r];
        }
  }
}

// ---------------- launch ----------------

extern "C" void kernel_launch(void* const* d_in, const int* in_sizes, int n_in,
                              void* d_out, int out_size, void* d_ws, size_t ws_size,
                              hipStream_t stream) {
  const float* X  = (const float*)d_in[0];
  // d_in[1] att_mask (unused), d_in[2] S_n (zeros, passthrough)
  const float* Wq = (const float*)d_in[3];
  const float* Wk = (const float*)d_in[4];
  const float* Wv = (const float*)d_in[5];
  float* out = (float*)d_out;

  char* ws = (char*)d_ws;
  short* Xb  = (short*)(ws);                 // 16,777,216  X bf16 [B*T, I]
  short* Wtq = (short*)(ws + 16777216);      //  2,097,152  Wq^T bf16 [c][i]
  short* Wtk = (short*)(ws + 18874368);      //  2,097,152
  short* Wtv = (short*)(ws + 20971520);      //  2,097,152
  short* Qb  = (short*)(ws + 23068672);      // 16,777,216  [B*T, C]
  short* Kb  = (short*)(ws + 39845888);      // 16,777,216
  short* Vt  = (short*)(ws + 56623104);      // 16,777,216  [B, I, T]
  short* P   = (short*)(ws + 73400320);      // 67,108,864  [B, T, T]

  // main out region fully written by k_pv plain stores; zero only S_n tail.
  const size_t mainN = (size_t)2 * T_SEQ * C_DIM;   // 8,388,608 floats
  hipMemsetAsync((char*)d_out + mainN * 4, 0,
                 ((size_t)out_size - mainN) * 4, stream);

  k_convX  <<<dim3(8192),       dim3(256), 0, stream>>>(X, Xb);
  k_convWt <<<dim3(32, 32, 3),  dim3(256), 0, stream>>>(Wq, Wk, Wv, Wtq, Wtk, Wtv);
  k_proj   <<<dim3(512, 3),     dim3(256), 0, stream>>>(Xb, Wtq, Wtk, Wtv, Qb, Kb, Vt);
  k_scores <<<dim3(528, 2),     dim3(256), 0, stream>>>(Qb, Kb, P);
  k_pv     <<<dim3(16, 8, 2),   dim3(256), 0, stream>>>(Vt, P, out);
}